// Round 5
// baseline (129.540 us; speedup 1.0000x reference)
//
#include <hip/hip_runtime.h>
#include <hip/hip_bf16.h>
#include <stdint.h>

#define BSZ 64
#define NRG 36
#define VD  2048
#define QD  1024
#define CS  512
#define RD  256
#define KP  2080                 // 2052 padded to 32
#define MR  (BSZ*NRG)            // 2304
#define TRI  666                 // upper-triangle pairs (i<=j) per batch
#define TRIQ 768                 // padded per-batch rows: 12 chunks of 64

typedef __bf16 bf16x8 __attribute__((ext_vector_type(8)));
typedef float  f32x4  __attribute__((ext_vector_type(4)));

static __device__ __forceinline__ f32x4 mfma16(bf16x8 a, bf16x8 b, f32x4 c) {
    return __builtin_amdgcn_mfma_f32_16x16x32_bf16(a, b, c, 0, 0, 0);
}

// async global->LDS, 16B per lane (dest = wave-uniform base + lane*16)
static __device__ __forceinline__ void load_lds16(const __bf16* g, __bf16* l) {
    __builtin_amdgcn_global_load_lds(
        (const __attribute__((address_space(1))) uint32_t*)(const void*)g,
        (__attribute__((address_space(3))) uint32_t*)(void*)l,
        16, 0, 0);
}

static __device__ __forceinline__ void wait_vm0_barrier() {
    asm volatile("s_waitcnt vmcnt(0)" ::: "memory");
    __builtin_amdgcn_s_barrier();
}

// stage one 16KB weight k-tile (4 g-rows x 256 cols x 8) : 4 chunks/thread
static __device__ __forceinline__ void stage_w(const __bf16* __restrict__ Wg,
                                               int kt, __bf16* dst, int tid) {
    #pragma unroll
    for (int it = 0; it < 4; ++it) {
        int c = tid + it * 256;
        load_lds16(Wg + (size_t)kt * (RD * 32) + (size_t)c * 8, dst + (size_t)c * 8);
    }
}

// ---- triangular index LUT: t -> (i<<8|j), i<=j, clamped past TRI ----
__global__ void k_lut(int* __restrict__ lut) {
    int t = threadIdx.x;
    if (t >= TRIQ) return;
    int tt = (t < TRI) ? t : (TRI - 1);
    int i = 0;
    while (tt >= NRG - i) { tt -= NRG - i; ++i; }
    lut[t] = (i << 8) | (i + tt);
}

// ---- prep: Xc_bf16 [MR][KP] = [X | pos | 0-pad] (row-major) ----
__global__ void k_prep_xc(const float* __restrict__ X, const float* __restrict__ pos,
                          __bf16* __restrict__ Xc) {
    int r = blockIdx.x;
    const float* xr = X + (size_t)r * VD;
    const float* pr = pos + (size_t)r * 4;
    __bf16* o = Xc + (size_t)r * KP;
    for (int c = threadIdx.x; c < KP; c += 256) {
        float v = 0.f;
        if (c < VD) v = xr[c];
        else if (c < VD + 4) v = pr[c - VD];
        o[c] = (__bf16)v;
    }
}

// ---- prep: g-major weight layout Wg[k/8][N][8] <- W[k][n], zero-pad k>=K ----
__global__ __launch_bounds__(256) void k_prep_wg(
    const float* __restrict__ W, __bf16* __restrict__ Wg, int K, int N) {
    int g = blockIdx.y * 4 + (threadIdx.x >> 6);
    int n = blockIdx.x * 64 + (threadIdx.x & 63);
    bf16x8 v;
    #pragma unroll
    for (int e = 0; e < 8; ++e) {
        int k = g * 8 + e;
        v[e] = (__bf16)((k < K) ? W[(size_t)k * N + n] : 0.f);
    }
    *(bf16x8*)(Wg + ((size_t)g * N + n) * 8) = v;
}

// ---- Qp[b][c] = relu(Q[b]@Wq[:,c] + bq[c]) fp32, split-K parallel ----
__global__ __launch_bounds__(256) void k_qproj(
    const float* __restrict__ Q, const float* __restrict__ Wq,
    const float* __restrict__ bq, float* __restrict__ Qp) {
    int b   = blockIdx.x;
    int col = blockIdx.y * 64 + (threadIdx.x & 63);
    int ks  = threadIdx.x >> 6;
    const float* q = Q  + (size_t)b * QD + ks * 256;
    const float* w = Wq + (size_t)(ks * 256) * CS + col;
    float acc = 0.f;
    #pragma unroll 8
    for (int k = 0; k < 256; ++k)
        acc = fmaf(q[k], w[(size_t)k * CS], acc);
    __shared__ float red[256];
    red[threadIdx.x] = acc;
    __syncthreads();
    if (ks == 0) {
        float v = red[threadIdx.x] + red[threadIdx.x + 64]
                + red[threadIdx.x + 128] + red[threadIdx.x + 192] + bq[col];
        Qp[(size_t)b * CS + col] = fmaxf(v, 0.f);
    }
}

// ---- G1: Xs = relu(Xc @ Wv + bv) + Qp[b], 64x64 tiles, 2-phase pipelined ----
__global__ __launch_bounds__(256, 4) void k_g1(
    const __bf16* __restrict__ Xc,   // [MR][KP]
    const __bf16* __restrict__ Wvg,  // [KP/8][CS][8]
    const float* __restrict__ bv,
    const float* __restrict__ Qp,    // [BSZ][CS]
    __bf16* __restrict__ Xs)         // [MR][CS]
{
    __shared__ __align__(16) __bf16 sA[2][4 * 64 * 8];  // [g][row][8], 4KB each
    __shared__ __align__(16) __bf16 sB[2][4 * 64 * 8];

    const int tid = threadIdx.x;
    const int lane = tid & 63;
    const int w = tid >> 6;
    const int wm = w & 1, wn = w >> 1;
    const int l15 = lane & 15, l4 = lane >> 4;
    const int m0 = blockIdx.x * 64;
    const int n0 = blockIdx.y * 64;
    const int sg = tid >> 6;     // staging g-chunk
    const int sr = tid & 63;     // staging row/col

    auto stage = [&](int kt, int bsel) {
        // A tile -> [g][row][8]
        load_lds16(Xc + (size_t)(m0 + sr) * KP + kt * 32 + sg * 8,
                   &sA[bsel][0] + (size_t)tid * 8);
        // B tile -> [g][col][8]
        load_lds16(Wvg + ((size_t)(kt * 4 + sg) * CS + n0 + sr) * 8,
                   &sB[bsel][0] + (size_t)tid * 8);
    };

    stage(0, 0);
    wait_vm0_barrier();

    f32x4 acc[2][2] = {};
    constexpr int NKT = KP / 32;   // 65
    for (int kt = 0; kt < NKT; ++kt) {
        const int cur = kt & 1;
        if (kt < NKT - 1) stage(kt + 1, cur ^ 1);
        const __bf16* a_base = &sA[cur][0];
        const __bf16* b_base = &sB[cur][0];
        bf16x8 af[2], bf[2];
        #pragma unroll
        for (int f = 0; f < 2; ++f)
            af[f] = *(const bf16x8*)(a_base + ((size_t)l4 * 64 + wm * 32 + f * 16 + l15) * 8);
        #pragma unroll
        for (int g = 0; g < 2; ++g)
            bf[g] = *(const bf16x8*)(b_base + ((size_t)l4 * 64 + wn * 32 + g * 16 + l15) * 8);
        __builtin_amdgcn_s_setprio(1);
        #pragma unroll
        for (int f = 0; f < 2; ++f)
            #pragma unroll
            for (int g = 0; g < 2; ++g)
                acc[f][g] = mfma16(af[f], bf[g], acc[f][g]);
        __builtin_amdgcn_s_setprio(0);
        wait_vm0_barrier();
    }

    #pragma unroll
    for (int f = 0; f < 2; ++f) {
        int row0 = m0 + wm * 32 + f * 16 + l4 * 4;
        #pragma unroll
        for (int g = 0; g < 2; ++g) {
            int col = n0 + wn * 32 + g * 16 + l15;
            float bb = bv[col];
            #pragma unroll
            for (int r = 0; r < 4; ++r) {
                int row = row0 + r;
                float v = fmaxf(acc[f][g][r] + bb, 0.f) + Qp[(size_t)(row / NRG) * CS + col];
                Xs[(size_t)row * CS + col] = (__bf16)v;
            }
        }
    }
}

// ---- fused G2+G3, 2-phase pipelined ----
__global__ __launch_bounds__(256, 2) void k_g23(
    const __bf16* __restrict__ Xs,   // [MR][CS]
    const __bf16* __restrict__ W1g,  // [CS/8][RD][8]
    const __bf16* __restrict__ W2g,  // [RD/8][RD][8]
    const float* __restrict__ b1,
    const float* __restrict__ b2,
    float* __restrict__ Out,         // [BSZ][NRG][NRG][RD]
    const int* __restrict__ lut)
{
    __shared__ __align__(16) __bf16 sB[2][4 * RD * 8];   // 2 x 16 KB
    __shared__ __align__(16) __bf16 sH[32 * 64 * 8];     // 32 KB [g2][row][8]

    const int tid = threadIdx.x;
    const int lane = tid & 63;
    const int w = tid >> 6;
    const int wm = w & 1, wn = w >> 1;   // wave = 32 rows x 128 cols
    const int l15 = lane & 15, l4 = lane >> 4;
    const int b = blockIdx.y;
    const int r_base = blockIdx.x * 64;

    const __bf16* xpi[2];
    const __bf16* xpj[2];
    #pragma unroll
    for (int f = 0; f < 2; ++f) {
        int t = r_base + wm * 32 + f * 16 + l15;
        int ij = lut[t];
        int i = ij >> 8, j = ij & 255;
        xpi[f] = Xs + (size_t)(b * NRG + i) * CS + l4 * 8;
        xpj[f] = Xs + (size_t)(b * NRG + j) * CS + l4 * 8;
    }

    // ---- prologue: stage W1 tile0 + pair regs for kt0 ----
    stage_w(W1g, 0, &sB[0][0], tid);
    bf16x8 xi[2], xj[2];
    #pragma unroll
    for (int f = 0; f < 2; ++f) { xi[f] = *(const bf16x8*)xpi[f]; xj[f] = *(const bf16x8*)xpj[f]; }
    wait_vm0_barrier();

    // ---- stage 1: K=512, 16 k-tiles ----
    f32x4 acc[2][8] = {};
    #pragma unroll
    for (int kt = 0; kt < 16; ++kt) {
        const int cur = kt & 1;
        bf16x8 xin[2], xjn[2];
        if (kt < 15) {
            stage_w(W1g, kt + 1, &sB[cur ^ 1][0], tid);
            #pragma unroll
            for (int f = 0; f < 2; ++f) {
                xin[f] = *(const bf16x8*)(xpi[f] + (kt + 1) * 32);
                xjn[f] = *(const bf16x8*)(xpj[f] + (kt + 1) * 32);
            }
        } else {
            stage_w(W2g, 0, &sB[cur ^ 1][0], tid);   // prefetch stage-2 tile0
        }
        bf16x8 af[2];
        #pragma unroll
        for (int f = 0; f < 2; ++f)
            #pragma unroll
            for (int e = 0; e < 8; ++e)
                af[f][e] = (__bf16)((float)xi[f][e] * (float)xj[f][e]);
        const __bf16* b_base = &sB[cur][0];
        __builtin_amdgcn_s_setprio(1);
        #pragma unroll
        for (int g = 0; g < 8; ++g) {
            bf16x8 bfr = *(const bf16x8*)(b_base + ((size_t)l4 * RD + wn * 128 + g * 16 + l15) * 8);
            acc[0][g] = mfma16(af[0], bfr, acc[0][g]);
            acc[1][g] = mfma16(af[1], bfr, acc[1][g]);
        }
        __builtin_amdgcn_s_setprio(0);
        if (kt < 15) {
            #pragma unroll
            for (int f = 0; f < 2; ++f) { xi[f] = xin[f]; xj[f] = xjn[f]; }
            wait_vm0_barrier();
        }
    }

    // ---- transition: H = relu(acc+b1) -> sH[g2][row][8] ----
    #pragma unroll
    for (int g = 0; g < 8; ++g) {
        int col = wn * 128 + g * 16 + l15;
        float bb = b1[col];
        int g2 = col >> 3, e = col & 7;
        #pragma unroll
        for (int f = 0; f < 2; ++f) {
            int row0 = wm * 32 + f * 16 + l4 * 4;
            #pragma unroll
            for (int r = 0; r < 4; ++r) {
                float v = fmaxf(acc[f][g][r] + bb, 0.f);
                sH[((size_t)g2 * 64 + row0 + r) * 8 + e] = (__bf16)v;
            }
        }
    }
    asm volatile("s_waitcnt vmcnt(0) lgkmcnt(0)" ::: "memory");
    __builtin_amdgcn_s_barrier();

    // ---- stage 2: K=256, 8 k-tiles (tile0 already in sB[0]) ----
    f32x4 acc2[2][8] = {};
    #pragma unroll
    for (int kt = 0; kt < 8; ++kt) {
        const int cur = kt & 1;
        if (kt < 7) stage_w(W2g, kt + 1, &sB[cur ^ 1][0], tid);
        bf16x8 ah[2];
        #pragma unroll
        for (int f = 0; f < 2; ++f) {
            int row = wm * 32 + f * 16 + l15;
            ah[f] = *(const bf16x8*)(sH + ((size_t)(kt * 4 + l4) * 64 + row) * 8);
        }
        const __bf16* b_base = &sB[cur][0];
        __builtin_amdgcn_s_setprio(1);
        #pragma unroll
        for (int g = 0; g < 8; ++g) {
            bf16x8 bfr = *(const bf16x8*)(b_base + ((size_t)l4 * RD + wn * 128 + g * 16 + l15) * 8);
            acc2[0][g] = mfma16(ah[0], bfr, acc2[0][g]);
            acc2[1][g] = mfma16(ah[1], bfr, acc2[1][g]);
        }
        __builtin_amdgcn_s_setprio(0);
        if (kt < 7) wait_vm0_barrier();
    }

    // ---- epilogue: dual-store fp32 ----
    float bias2[8];
    #pragma unroll
    for (int g = 0; g < 8; ++g) bias2[g] = b2[wn * 128 + g * 16 + l15];
    #pragma unroll
    for (int f = 0; f < 2; ++f) {
        int row_l = wm * 32 + f * 16 + l4 * 4;
        #pragma unroll
        for (int r = 0; r < 4; ++r) {
            int t = r_base + row_l + r;
            if (t < TRI) {
                int ij = lut[t];
                int i = ij >> 8, j = ij & 255;
                float* o1 = Out + (size_t)((b * NRG + i) * NRG + j) * RD;
                float* o2 = Out + (size_t)((b * NRG + j) * NRG + i) * RD;
                #pragma unroll
                for (int g = 0; g < 8; ++g) {
                    int col = wn * 128 + g * 16 + l15;
                    float v = fmaxf(acc2[f][g][r] + bias2[g], 0.f);
                    o1[col] = v;
                    o2[col] = v;
                }
            }
        }
    }
}

extern "C" void kernel_launch(void* const* d_in, const int* in_sizes, int n_in,
                              void* d_out, int out_size, void* d_ws, size_t ws_size,
                              hipStream_t stream) {
    const float* X   = (const float*)d_in[0];
    const float* Q   = (const float*)d_in[1];
    const float* pos = (const float*)d_in[2];
    const float* Wv  = (const float*)d_in[3];
    const float* bv  = (const float*)d_in[4];
    const float* Wq  = (const float*)d_in[5];
    const float* bq  = (const float*)d_in[6];
    const float* W1  = (const float*)d_in[7];
    const float* b1  = (const float*)d_in[8];
    const float* W2  = (const float*)d_in[9];
    const float* b2  = (const float*)d_in[10];

    char* ws = (char*)d_ws;
    size_t off = 0;
    auto alloc = [&](size_t bytes) {
        char* p = ws + off;
        off = (off + bytes + 255) & ~(size_t)255;
        return p;
    };
    __bf16* Xc  = (__bf16*)alloc((size_t)MR * KP * 2);
    __bf16* Wvg = (__bf16*)alloc((size_t)(KP/8) * CS * 8 * 2);
    __bf16* W1g = (__bf16*)alloc((size_t)(CS/8) * RD * 8 * 2);
    __bf16* W2g = (__bf16*)alloc((size_t)(RD/8) * RD * 8 * 2);
    float*  Qp  = (float*) alloc((size_t)BSZ * CS * 4);
    __bf16* Xs  = (__bf16*)alloc((size_t)MR * CS * 2);
    int*    lut = (int*)   alloc((size_t)TRIQ * 4);

    hipLaunchKernelGGL(k_lut,     dim3(1),        dim3(TRIQ), 0, stream, lut);
    hipLaunchKernelGGL(k_prep_xc, dim3(MR),       dim3(256),  0, stream, X, pos, Xc);
    hipLaunchKernelGGL(k_prep_wg, dim3(CS/64, KP/32), dim3(256), 0, stream, Wv, Wvg, VD + 4, CS);
    hipLaunchKernelGGL(k_prep_wg, dim3(RD/64, CS/32), dim3(256), 0, stream, W1, W1g, CS, RD);
    hipLaunchKernelGGL(k_prep_wg, dim3(RD/64, RD/32), dim3(256), 0, stream, W2, W2g, RD, RD);
    hipLaunchKernelGGL(k_qproj,   dim3(BSZ, CS/64),   dim3(256), 0, stream, Q, Wq, bq, Qp);

    hipLaunchKernelGGL(k_g1,  dim3(MR/64, CS/64), dim3(256), 0, stream,
                       Xc, Wvg, bv, Qp, Xs);
    hipLaunchKernelGGL(k_g23, dim3(TRIQ/64, BSZ), dim3(256), 0, stream,
                       Xs, W1g, W2g, b1, b2, (float*)d_out, (const int*)lut);
}

// Round 6
// 124.436 us; speedup vs baseline: 1.0410x; 1.0410x over previous
//
#include <hip/hip_runtime.h>
#include <hip/hip_bf16.h>
#include <stdint.h>

#define BSZ 64
#define NRG 36
#define VD  2048
#define QD  1024
#define CS  512
#define RD  256
#define KP  2080                 // 2052 padded to 32
#define MR  (BSZ*NRG)            // 2304
#define TRI  666                 // upper-triangle pairs (i<=j) per batch
#define TRIQ 768                 // padded per-batch rows: 12 chunks of 64

typedef __bf16 bf16x8 __attribute__((ext_vector_type(8)));
typedef float  f32x4  __attribute__((ext_vector_type(4)));

static __device__ __forceinline__ f32x4 mfma16(bf16x8 a, bf16x8 b, f32x4 c) {
    return __builtin_amdgcn_mfma_f32_16x16x32_bf16(a, b, c, 0, 0, 0);
}

// async global->LDS, 16B per lane (dest = wave-uniform base + lane*16)
static __device__ __forceinline__ void load_lds16(const __bf16* g, __bf16* l) {
    __builtin_amdgcn_global_load_lds(
        (const __attribute__((address_space(1))) uint32_t*)(const void*)g,
        (__attribute__((address_space(3))) uint32_t*)(void*)l,
        16, 0, 0);
}

static __device__ __forceinline__ void wait_vm0_barrier() {
    asm volatile("s_waitcnt vmcnt(0)" ::: "memory");
    __builtin_amdgcn_s_barrier();
}

// ---- triangular index LUT: t -> (i<<8|j), i<=j, clamped past TRI ----
__global__ void k_lut(int* __restrict__ lut) {
    int t = threadIdx.x;
    if (t >= TRIQ) return;
    int tt = (t < TRI) ? t : (TRI - 1);
    int i = 0;
    while (tt >= NRG - i) { tt -= NRG - i; ++i; }
    lut[t] = (i << 8) | (i + tt);
}

// ---- prep: Xc_bf16 [MR][KP] = [X | pos | 0-pad] (row-major) ----
__global__ void k_prep_xc(const float* __restrict__ X, const float* __restrict__ pos,
                          __bf16* __restrict__ Xc) {
    int r = blockIdx.x;
    const float* xr = X + (size_t)r * VD;
    const float* pr = pos + (size_t)r * 4;
    __bf16* o = Xc + (size_t)r * KP;
    for (int c = threadIdx.x; c < KP; c += 256) {
        float v = 0.f;
        if (c < VD) v = xr[c];
        else if (c < VD + 4) v = pr[c - VD];
        o[c] = (__bf16)v;
    }
}

// ---- prep: g-major weight layout Wg[k/8][N][8] <- W[k][n], zero-pad k>=K ----
__global__ __launch_bounds__(256) void k_prep_wg(
    const float* __restrict__ W, __bf16* __restrict__ Wg, int K, int N) {
    int g = blockIdx.y * 4 + (threadIdx.x >> 6);
    int n = blockIdx.x * 64 + (threadIdx.x & 63);
    bf16x8 v;
    #pragma unroll
    for (int e = 0; e < 8; ++e) {
        int k = g * 8 + e;
        v[e] = (__bf16)((k < K) ? W[(size_t)k * N + n] : 0.f);
    }
    *(bf16x8*)(Wg + ((size_t)g * N + n) * 8) = v;
}

// ---- Qp[b][c] = relu(Q[b]@Wq[:,c] + bq[c]) fp32, split-K parallel ----
__global__ __launch_bounds__(256) void k_qproj(
    const float* __restrict__ Q, const float* __restrict__ Wq,
    const float* __restrict__ bq, float* __restrict__ Qp) {
    int b   = blockIdx.x;
    int col = blockIdx.y * 64 + (threadIdx.x & 63);
    int ks  = threadIdx.x >> 6;
    const float* q = Q  + (size_t)b * QD + ks * 256;
    const float* w = Wq + (size_t)(ks * 256) * CS + col;
    float acc = 0.f;
    #pragma unroll 8
    for (int k = 0; k < 256; ++k)
        acc = fmaf(q[k], w[(size_t)k * CS], acc);
    __shared__ float red[256];
    red[threadIdx.x] = acc;
    __syncthreads();
    if (ks == 0) {
        float v = red[threadIdx.x] + red[threadIdx.x + 64]
                + red[threadIdx.x + 128] + red[threadIdx.x + 192] + bq[col];
        Qp[(size_t)b * CS + col] = fmaxf(v, 0.f);
    }
}

// ---- G1: Xs = relu(Xc @ Wv + bv) + Qp[b], 64x64 tiles, 2-phase pipelined ----
__global__ __launch_bounds__(256, 4) void k_g1(
    const __bf16* __restrict__ Xc,   // [MR][KP]
    const __bf16* __restrict__ Wvg,  // [KP/8][CS][8]
    const float* __restrict__ bv,
    const float* __restrict__ Qp,    // [BSZ][CS]
    __bf16* __restrict__ Xs)         // [MR][CS]
{
    __shared__ __align__(16) __bf16 sA[2][4 * 64 * 8];  // [g][row][8], 4KB each
    __shared__ __align__(16) __bf16 sB[2][4 * 64 * 8];

    const int tid = threadIdx.x;
    const int lane = tid & 63;
    const int w = tid >> 6;
    const int wm = w & 1, wn = w >> 1;
    const int l15 = lane & 15, l4 = lane >> 4;
    const int m0 = blockIdx.x * 64;
    const int n0 = blockIdx.y * 64;
    const int sg = tid >> 6;     // staging g-chunk
    const int sr = tid & 63;     // staging row/col

    auto stage = [&](int kt, int bsel) {
        load_lds16(Xc + (size_t)(m0 + sr) * KP + kt * 32 + sg * 8,
                   &sA[bsel][0] + (size_t)tid * 8);
        load_lds16(Wvg + ((size_t)(kt * 4 + sg) * CS + n0 + sr) * 8,
                   &sB[bsel][0] + (size_t)tid * 8);
    };

    stage(0, 0);
    wait_vm0_barrier();

    f32x4 acc[2][2] = {};
    constexpr int NKT = KP / 32;   // 65
    for (int kt = 0; kt < NKT; ++kt) {
        const int cur = kt & 1;
        if (kt < NKT - 1) stage(kt + 1, cur ^ 1);
        const __bf16* a_base = &sA[cur][0];
        const __bf16* b_base = &sB[cur][0];
        bf16x8 af[2], bf[2];
        #pragma unroll
        for (int f = 0; f < 2; ++f)
            af[f] = *(const bf16x8*)(a_base + ((size_t)l4 * 64 + wm * 32 + f * 16 + l15) * 8);
        #pragma unroll
        for (int g = 0; g < 2; ++g)
            bf[g] = *(const bf16x8*)(b_base + ((size_t)l4 * 64 + wn * 32 + g * 16 + l15) * 8);
        __builtin_amdgcn_s_setprio(1);
        #pragma unroll
        for (int f = 0; f < 2; ++f)
            #pragma unroll
            for (int g = 0; g < 2; ++g)
                acc[f][g] = mfma16(af[f], bf[g], acc[f][g]);
        __builtin_amdgcn_s_setprio(0);
        wait_vm0_barrier();
    }

    #pragma unroll
    for (int f = 0; f < 2; ++f) {
        int row0 = m0 + wm * 32 + f * 16 + l4 * 4;
        #pragma unroll
        for (int g = 0; g < 2; ++g) {
            int col = n0 + wn * 32 + g * 16 + l15;
            float bb = bv[col];
            #pragma unroll
            for (int r = 0; r < 4; ++r) {
                int row = row0 + r;
                float v = fmaxf(acc[f][g][r] + bb, 0.f) + Qp[(size_t)(row / NRG) * CS + col];
                Xs[(size_t)row * CS + col] = (__bf16)v;
            }
        }
    }
}

// ---- fused G2+G3 v3: barrier-free, weights direct L2 -> registers ----
// stage1: acc = pair @ W1 (K=512), W1 frags prefetched in regs, NO barriers
// transition: H -> sH (one barrier)
// stage2: acc2 = H @ W2 (K=256), W2 frags in regs, sH reads, no barriers
__global__ __launch_bounds__(256, 3) void k_g23(
    const __bf16* __restrict__ Xs,   // [MR][CS]
    const __bf16* __restrict__ W1g,  // [CS/8][RD][8]
    const __bf16* __restrict__ W2g,  // [RD/8][RD][8]
    const float* __restrict__ b1,
    const float* __restrict__ b2,
    float* __restrict__ Out,         // [BSZ][NRG][NRG][RD]
    const int* __restrict__ lut)
{
    __shared__ __align__(16) __bf16 sH[32 * 64 * 8];  // 32 KB [g2][row][8]

    const int tid = threadIdx.x;
    const int lane = tid & 63;
    const int w = tid >> 6;
    const int wm = w & 1, wn = w >> 1;   // wave = 32 rows x 128 cols
    const int l15 = lane & 15, l4 = lane >> 4;
    const int b = blockIdx.y;
    const int r_base = blockIdx.x * 64;

    const __bf16* xpi[2];
    const __bf16* xpj[2];
    #pragma unroll
    for (int f = 0; f < 2; ++f) {
        int t = r_base + wm * 32 + f * 16 + l15;
        int ij = lut[t];
        int i = ij >> 8, j = ij & 255;
        xpi[f] = Xs + (size_t)(b * NRG + i) * CS + l4 * 8;
        xpj[f] = Xs + (size_t)(b * NRG + j) * CS + l4 * 8;
    }

    // per-lane W fragment base: frag g at +g*128 elems, k-tile kt at +kt*4*RD*8
    const __bf16* w1p = W1g + ((size_t)l4 * RD + wn * 128 + l15) * 8;
    const __bf16* w2p = W2g + ((size_t)l4 * RD + wn * 128 + l15) * 8;

    f32x4 acc[2][8] = {};
    bf16x8 wf[2][8];
    bf16x8 xi[2], xj[2];

    // prologue: W1 tile 0 + pair regs for kt 0
    #pragma unroll
    for (int g = 0; g < 8; ++g) wf[0][g] = *(const bf16x8*)(w1p + (size_t)g * 128);
    #pragma unroll
    for (int f = 0; f < 2; ++f) {
        xi[f] = *(const bf16x8*)xpi[f];
        xj[f] = *(const bf16x8*)xpj[f];
    }

    // ---- stage 1: K=512, 16 k-tiles, zero barriers ----
    #pragma unroll
    for (int kt = 0; kt < 16; ++kt) {
        const int cur = kt & 1, nxt = cur ^ 1;
        // consume xi/xj -> af, then regs are free for next-tile prefetch
        bf16x8 af[2];
        #pragma unroll
        for (int f = 0; f < 2; ++f)
            #pragma unroll
            for (int e = 0; e < 8; ++e)
                af[f][e] = (__bf16)((float)xi[f][e] * (float)xj[f][e]);
        if (kt < 15) {
            const __bf16* wp = w1p + (size_t)(kt + 1) * (4 * RD * 8);
            #pragma unroll
            for (int g = 0; g < 8; ++g) wf[nxt][g] = *(const bf16x8*)(wp + (size_t)g * 128);
            #pragma unroll
            for (int f = 0; f < 2; ++f) {
                xi[f] = *(const bf16x8*)(xpi[f] + (kt + 1) * 32);
                xj[f] = *(const bf16x8*)(xpj[f] + (kt + 1) * 32);
            }
        } else {
            // prefetch stage-2 W2 tile 0
            #pragma unroll
            for (int g = 0; g < 8; ++g) wf[nxt][g] = *(const bf16x8*)(w2p + (size_t)g * 128);
        }
        __builtin_amdgcn_s_setprio(1);
        #pragma unroll
        for (int g = 0; g < 8; ++g) {
            acc[0][g] = mfma16(af[0], wf[cur][g], acc[0][g]);
            acc[1][g] = mfma16(af[1], wf[cur][g], acc[1][g]);
        }
        __builtin_amdgcn_s_setprio(0);
    }

    // ---- transition: H = relu(acc+b1) -> sH[g2][row][8] ; ONE barrier ----
    #pragma unroll
    for (int g = 0; g < 8; ++g) {
        int col = wn * 128 + g * 16 + l15;
        float bb = b1[col];
        int g2 = col >> 3, e = col & 7;
        #pragma unroll
        for (int f = 0; f < 2; ++f) {
            int row0 = wm * 32 + f * 16 + l4 * 4;
            #pragma unroll
            for (int r = 0; r < 4; ++r) {
                float v = fmaxf(acc[f][g][r] + bb, 0.f);
                sH[((size_t)g2 * 64 + row0 + r) * 8 + e] = (__bf16)v;
            }
        }
    }
    __syncthreads();

    // ---- stage 2: K=256, 8 k-tiles (W2 tile0 already in wf[0]) ----
    f32x4 acc2[2][8] = {};
    bf16x8 ah[2][2];
    #pragma unroll
    for (int f = 0; f < 2; ++f)
        ah[0][f] = *(const bf16x8*)(sH + ((size_t)l4 * 64 + wm * 32 + f * 16 + l15) * 8);

    #pragma unroll
    for (int kt = 0; kt < 8; ++kt) {
        const int cur = kt & 1, nxt = cur ^ 1;
        if (kt < 7) {
            const __bf16* wp = w2p + (size_t)(kt + 1) * (4 * RD * 8);
            #pragma unroll
            for (int g = 0; g < 8; ++g) wf[nxt][g] = *(const bf16x8*)(wp + (size_t)g * 128);
            #pragma unroll
            for (int f = 0; f < 2; ++f)
                ah[nxt][f] = *(const bf16x8*)(sH + ((size_t)((kt + 1) * 4 + l4) * 64
                                                   + wm * 32 + f * 16 + l15) * 8);
        }
        __builtin_amdgcn_s_setprio(1);
        #pragma unroll
        for (int g = 0; g < 8; ++g) {
            acc2[0][g] = mfma16(ah[cur][0], wf[cur][g], acc2[0][g]);
            acc2[1][g] = mfma16(ah[cur][1], wf[cur][g], acc2[1][g]);
        }
        __builtin_amdgcn_s_setprio(0);
    }

    // ---- epilogue: dual-store fp32 ----
    float bias2[8];
    #pragma unroll
    for (int g = 0; g < 8; ++g) bias2[g] = b2[wn * 128 + g * 16 + l15];
    #pragma unroll
    for (int f = 0; f < 2; ++f) {
        int row_l = wm * 32 + f * 16 + l4 * 4;
        #pragma unroll
        for (int r = 0; r < 4; ++r) {
            int t = r_base + row_l + r;
            if (t < TRI) {
                int ij = lut[t];
                int i = ij >> 8, j = ij & 255;
                float* o1 = Out + (size_t)((b * NRG + i) * NRG + j) * RD;
                float* o2 = Out + (size_t)((b * NRG + j) * NRG + i) * RD;
                #pragma unroll
                for (int g = 0; g < 8; ++g) {
                    int col = wn * 128 + g * 16 + l15;
                    float v = fmaxf(acc2[f][g][r] + bias2[g], 0.f);
                    o1[col] = v;
                    o2[col] = v;
                }
            }
        }
    }
}

extern "C" void kernel_launch(void* const* d_in, const int* in_sizes, int n_in,
                              void* d_out, int out_size, void* d_ws, size_t ws_size,
                              hipStream_t stream) {
    const float* X   = (const float*)d_in[0];
    const float* Q   = (const float*)d_in[1];
    const float* pos = (const float*)d_in[2];
    const float* Wv  = (const float*)d_in[3];
    const float* bv  = (const float*)d_in[4];
    const float* Wq  = (const float*)d_in[5];
    const float* bq  = (const float*)d_in[6];
    const float* W1  = (const float*)d_in[7];
    const float* b1  = (const float*)d_in[8];
    const float* W2  = (const float*)d_in[9];
    const float* b2  = (const float*)d_in[10];

    char* ws = (char*)d_ws;
    size_t off = 0;
    auto alloc = [&](size_t bytes) {
        char* p = ws + off;
        off = (off + bytes + 255) & ~(size_t)255;
        return p;
    };
    __bf16* Xc  = (__bf16*)alloc((size_t)MR * KP * 2);
    __bf16* Wvg = (__bf16*)alloc((size_t)(KP/8) * CS * 8 * 2);
    __bf16* W1g = (__bf16*)alloc((size_t)(CS/8) * RD * 8 * 2);
    __bf16* W2g = (__bf16*)alloc((size_t)(RD/8) * RD * 8 * 2);
    float*  Qp  = (float*) alloc((size_t)BSZ * CS * 4);
    __bf16* Xs  = (__bf16*)alloc((size_t)MR * CS * 2);
    int*    lut = (int*)   alloc((size_t)TRIQ * 4);

    hipLaunchKernelGGL(k_lut,     dim3(1),        dim3(TRIQ), 0, stream, lut);
    hipLaunchKernelGGL(k_prep_xc, dim3(MR),       dim3(256),  0, stream, X, pos, Xc);
    hipLaunchKernelGGL(k_prep_wg, dim3(CS/64, KP/32), dim3(256), 0, stream, Wv, Wvg, VD + 4, CS);
    hipLaunchKernelGGL(k_prep_wg, dim3(RD/64, CS/32), dim3(256), 0, stream, W1, W1g, CS, RD);
    hipLaunchKernelGGL(k_prep_wg, dim3(RD/64, RD/32), dim3(256), 0, stream, W2, W2g, RD, RD);
    hipLaunchKernelGGL(k_qproj,   dim3(BSZ, CS/64),   dim3(256), 0, stream, Q, Wq, bq, Qp);

    hipLaunchKernelGGL(k_g1,  dim3(MR/64, CS/64), dim3(256), 0, stream,
                       Xc, Wvg, bv, Qp, Xs);
    hipLaunchKernelGGL(k_g23, dim3(TRIQ/64, BSZ), dim3(256), 0, stream,
                       Xs, W1g, W2g, b1, b2, (float*)d_out, (const int*)lut);
}

// Round 7
// 107.955 us; speedup vs baseline: 1.1999x; 1.1527x over previous
//
#include <hip/hip_runtime.h>
#include <hip/hip_bf16.h>
#include <stdint.h>

#define BSZ 64
#define NRG 36
#define VD  2048
#define QD  1024
#define CS  512
#define RD  256
#define KP  2080                 // 2052 padded to 32
#define MR  (BSZ*NRG)            // 2304
#define TRI  666                 // upper-triangle pairs (i<=j) per batch
#define TRIQ 768                 // padded per-batch rows

typedef __bf16 bf16x8 __attribute__((ext_vector_type(8)));
typedef float  f32x4  __attribute__((ext_vector_type(4)));

static __device__ __forceinline__ f32x4 mfma16(bf16x8 a, bf16x8 b, f32x4 c) {
    return __builtin_amdgcn_mfma_f32_16x16x32_bf16(a, b, c, 0, 0, 0);
}

// async global->LDS, 16B per lane (dest = wave-uniform base + lane*16)
static __device__ __forceinline__ void load_lds16(const __bf16* g, __bf16* l) {
    __builtin_amdgcn_global_load_lds(
        (const __attribute__((address_space(1))) uint32_t*)(const void*)g,
        (__attribute__((address_space(3))) uint32_t*)(void*)l,
        16, 0, 0);
}

// ---- merged prep: Xc rows, 3 g-major weights, tri LUT, one launch ----
// grid: [0,MR) = Xc rows; [MR, MR+616) = weight tiles; MR+616 = lut
__global__ __launch_bounds__(256) void k_prep(
    const float* __restrict__ X, const float* __restrict__ pos,
    const float* __restrict__ Wv, const float* __restrict__ W1,
    const float* __restrict__ W2,
    __bf16* __restrict__ Xc, __bf16* __restrict__ Wvg,
    __bf16* __restrict__ W1g, __bf16* __restrict__ W2g,
    int* __restrict__ lut)
{
    int id = blockIdx.x;
    if (id < MR) {               // ---- Xc row: [X | pos | 0-pad] ----
        const float* xr = X + (size_t)id * VD;
        const float* pr = pos + (size_t)id * 4;
        __bf16* o = Xc + (size_t)id * KP;
        for (int c = threadIdx.x; c < KP; c += 256) {
            float v = 0.f;
            if (c < VD) v = xr[c];
            else if (c < VD + 4) v = pr[c - VD];
            o[c] = (__bf16)v;
        }
        return;
    }
    id -= MR;
    if (id < 520 + 64 + 32) {    // ---- weight tile -> Wg[k/8][N][8] ----
        const float* W; __bf16* Wg; int K, N, nbx;
        if (id < 520)      {          W = Wv; Wg = Wvg; K = VD + 4; N = CS; nbx = CS / 64; }
        else if (id < 584) { id -= 520; W = W1; Wg = W1g; K = CS;     N = RD; nbx = RD / 64; }
        else               { id -= 584; W = W2; Wg = W2g; K = RD;     N = RD; nbx = RD / 64; }
        int bx = id % nbx, by = id / nbx;
        int g = by * 4 + (threadIdx.x >> 6);
        int n = bx * 64 + (threadIdx.x & 63);
        bf16x8 v;
        #pragma unroll
        for (int e = 0; e < 8; ++e) {
            int k = g * 8 + e;
            v[e] = (__bf16)((k < K) ? W[(size_t)k * N + n] : 0.f);
        }
        *(bf16x8*)(Wg + ((size_t)g * N + n) * 8) = v;
        return;
    }
    // ---- lut ----
    for (int t = threadIdx.x; t < TRIQ; t += 256) {
        int tt = (t < TRI) ? t : (TRI - 1);
        int i = 0;
        while (tt >= NRG - i) { tt -= NRG - i; ++i; }
        lut[t] = (i << 8) | (i + tt);
    }
}

// ---- Qp[b][c] = relu(Q[b]@Wq[:,c] + bq[c]) fp32, split-K parallel ----
__global__ __launch_bounds__(256) void k_qproj(
    const float* __restrict__ Q, const float* __restrict__ Wq,
    const float* __restrict__ bq, float* __restrict__ Qp) {
    int b   = blockIdx.x;
    int col = blockIdx.y * 64 + (threadIdx.x & 63);
    int ks  = threadIdx.x >> 6;
    const float* q = Q  + (size_t)b * QD + ks * 256;
    const float* w = Wq + (size_t)(ks * 256) * CS + col;
    float acc = 0.f;
    #pragma unroll 8
    for (int k = 0; k < 256; ++k)
        acc = fmaf(q[k], w[(size_t)k * CS], acc);
    __shared__ float red[256];
    red[threadIdx.x] = acc;
    __syncthreads();
    if (ks == 0) {
        float v = red[threadIdx.x] + red[threadIdx.x + 64]
                + red[threadIdx.x + 128] + red[threadIdx.x + 192] + bq[col];
        Qp[(size_t)b * CS + col] = fmaxf(v, 0.f);
    }
}

// ---- G1: Xs = relu(Xc @ Wv + bv) + Qp[b] ----
// ring-4 LDS staging, counted vmcnt (loads stay in flight across barriers)
__global__ __launch_bounds__(256) void k_g1(
    const __bf16* __restrict__ Xc,   // [MR][KP]
    const __bf16* __restrict__ Wvg,  // [KP/8][CS][8]
    const float* __restrict__ bv,
    const float* __restrict__ Qp,    // [BSZ][CS]
    __bf16* __restrict__ Xs)         // [MR][CS]
{
    __shared__ __align__(16) __bf16 sA[4][4 * 64 * 8];  // [slot][g][row][8]
    __shared__ __align__(16) __bf16 sB[4][4 * 64 * 8];

    const int tid = threadIdx.x;
    const int lane = tid & 63;
    const int w = tid >> 6;
    const int wm = w & 1, wn = w >> 1;
    const int l15 = lane & 15, l4 = lane >> 4;
    const int m0 = blockIdx.x * 64;
    const int n0 = blockIdx.y * 64;
    const int sg = tid >> 6;     // staging g-chunk
    const int sr = tid & 63;     // staging row/col

    auto stage = [&](int kt, int slot) {
        load_lds16(Xc + (size_t)(m0 + sr) * KP + kt * 32 + sg * 8,
                   &sA[slot][0] + (size_t)tid * 8);
        load_lds16(Wvg + ((size_t)(kt * 4 + sg) * CS + n0 + sr) * 8,
                   &sB[slot][0] + (size_t)tid * 8);
    };

    constexpr int NKT = KP / 32;   // 65
    stage(0, 0);
    stage(1, 1);

    f32x4 acc[2][2] = {};
    for (int kt = 0; kt < NKT; ++kt) {
        if (kt + 2 < NKT) stage(kt + 2, (kt + 2) & 3);
        if (kt + 2 < NKT)      asm volatile("s_waitcnt vmcnt(4)" ::: "memory");
        else if (kt + 1 < NKT) asm volatile("s_waitcnt vmcnt(2)" ::: "memory");
        else                   asm volatile("s_waitcnt vmcnt(0)" ::: "memory");
        __builtin_amdgcn_s_barrier();

        const __bf16* a_base = &sA[kt & 3][0];
        const __bf16* b_base = &sB[kt & 3][0];
        bf16x8 af[2], bf[2];
        #pragma unroll
        for (int f = 0; f < 2; ++f)
            af[f] = *(const bf16x8*)(a_base + ((size_t)l4 * 64 + wm * 32 + f * 16 + l15) * 8);
        #pragma unroll
        for (int g = 0; g < 2; ++g)
            bf[g] = *(const bf16x8*)(b_base + ((size_t)l4 * 64 + wn * 32 + g * 16 + l15) * 8);
        __builtin_amdgcn_s_setprio(1);
        #pragma unroll
        for (int f = 0; f < 2; ++f)
            #pragma unroll
            for (int g = 0; g < 2; ++g)
                acc[f][g] = mfma16(af[f], bf[g], acc[f][g]);
        __builtin_amdgcn_s_setprio(0);
    }

    #pragma unroll
    for (int f = 0; f < 2; ++f) {
        int row0 = m0 + wm * 32 + f * 16 + l4 * 4;
        #pragma unroll
        for (int g = 0; g < 2; ++g) {
            int col = n0 + wn * 32 + g * 16 + l15;
            float bb = bv[col];
            #pragma unroll
            for (int r = 0; r < 4; ++r) {
                int row = row0 + r;
                float v = fmaxf(acc[f][g][r] + bb, 0.f) + Qp[(size_t)(row / NRG) * CS + col];
                Xs[(size_t)row * CS + col] = (__bf16)v;
            }
        }
    }
}

// ---- fused G2+G3 v4: named-register ping-pong (no dynamic indexing) ----
__global__ __launch_bounds__(256, 2) void k_g23(
    const __bf16* __restrict__ Xs,   // [MR][CS]
    const __bf16* __restrict__ W1g,  // [CS/8][RD][8]
    const __bf16* __restrict__ W2g,  // [RD/8][RD][8]
    const float* __restrict__ b1,
    const float* __restrict__ b2,
    float* __restrict__ Out,         // [BSZ][NRG][NRG][RD]
    const int* __restrict__ lut)
{
    __shared__ __align__(16) __bf16 sH[32 * 64 * 8];  // 32 KB [g2][row][8]

    const int tid = threadIdx.x;
    const int lane = tid & 63;
    const int w = tid >> 6;
    const int wm = w & 1, wn = w >> 1;   // wave = 32 rows x 128 cols
    const int l15 = lane & 15, l4 = lane >> 4;
    const int b = blockIdx.y;
    const int r_base = blockIdx.x * 64;

    const int t0 = r_base + wm * 32 + l15;
    const int ij0 = lut[t0], ij1 = lut[t0 + 16];
    const __bf16* xpi0 = Xs + (size_t)(b * NRG + (ij0 >> 8)) * CS + l4 * 8;
    const __bf16* xpj0 = Xs + (size_t)(b * NRG + (ij0 & 255)) * CS + l4 * 8;
    const __bf16* xpi1 = Xs + (size_t)(b * NRG + (ij1 >> 8)) * CS + l4 * 8;
    const __bf16* xpj1 = Xs + (size_t)(b * NRG + (ij1 & 255)) * CS + l4 * 8;

    const __bf16* w1p = W1g + ((size_t)l4 * RD + wn * 128 + l15) * 8;
    const __bf16* w2p = W2g + ((size_t)l4 * RD + wn * 128 + l15) * 8;

    f32x4 acc0[8] = {}, acc1[8] = {};
    bf16x8 wA[8], wB[8];
    bf16x8 xiA0, xiA1, xjA0, xjA1, xiB0, xiB1, xjB0, xjB1;

    // prologue: W1 tile 0 -> wA, pair tile 0 -> A set
    #pragma unroll
    for (int g = 0; g < 8; ++g) wA[g] = *(const bf16x8*)(w1p + (size_t)g * 128);
    xiA0 = *(const bf16x8*)xpi0; xiA1 = *(const bf16x8*)xpi1;
    xjA0 = *(const bf16x8*)xpj0; xjA1 = *(const bf16x8*)xpj1;

#define PF_W(WN, BASE, KT) { \
    const __bf16* wp_ = (BASE) + (size_t)(KT) * (4 * RD * 8); \
    _Pragma("unroll") for (int g = 0; g < 8; ++g) \
        WN[g] = *(const bf16x8*)(wp_ + (size_t)g * 128); }

#define PF_PAIR(XN0, XN1, XM0, XM1, KT) { \
    XN0 = *(const bf16x8*)(xpi0 + (KT) * 32); \
    XN1 = *(const bf16x8*)(xpi1 + (KT) * 32); \
    XM0 = *(const bf16x8*)(xpj0 + (KT) * 32); \
    XM1 = *(const bf16x8*)(xpj1 + (KT) * 32); }

#define S1_BODY(KT, WC, WN, XI0, XI1, XJ0, XJ1, XN0, XN1, XM0, XM1) { \
    bf16x8 af0, af1; \
    _Pragma("unroll") for (int e = 0; e < 8; ++e) { \
        af0[e] = (__bf16)((float)XI0[e] * (float)XJ0[e]); \
        af1[e] = (__bf16)((float)XI1[e] * (float)XJ1[e]); } \
    if ((KT) < 15) { PF_W(WN, w1p, (KT) + 1); PF_PAIR(XN0, XN1, XM0, XM1, (KT) + 1); } \
    else           { PF_W(WN, w2p, 0); } \
    __builtin_amdgcn_s_setprio(1); \
    _Pragma("unroll") for (int g = 0; g < 8; ++g) { \
        acc0[g] = mfma16(af0, WC[g], acc0[g]); \
        acc1[g] = mfma16(af1, WC[g], acc1[g]); } \
    __builtin_amdgcn_s_setprio(0); }

#define S1_PAIR2(K) \
    S1_BODY(2*(K),   wA, wB, xiA0, xiA1, xjA0, xjA1, xiB0, xiB1, xjB0, xjB1) \
    S1_BODY(2*(K)+1, wB, wA, xiB0, xiB1, xjB0, xjB1, xiA0, xiA1, xjA0, xjA1)

    S1_PAIR2(0) S1_PAIR2(1) S1_PAIR2(2) S1_PAIR2(3)
    S1_PAIR2(4) S1_PAIR2(5) S1_PAIR2(6) S1_PAIR2(7)
    // after KT=15: W2 tile 0 sits in wA

    // ---- transition: H = relu(acc+b1) -> sH[g2][row][8] ----
    {
        const int rw0 = wm * 32 + l4 * 4;
        #pragma unroll
        for (int g = 0; g < 8; ++g) {
            int col = wn * 128 + g * 16 + l15;
            float bb = b1[col];
            int g2 = col >> 3, e = col & 7;
            #pragma unroll
            for (int r = 0; r < 4; ++r) {
                sH[((size_t)g2 * 64 + rw0 + r) * 8 + e]      = (__bf16)fmaxf(acc0[g][r] + bb, 0.f);
                sH[((size_t)g2 * 64 + rw0 + 16 + r) * 8 + e] = (__bf16)fmaxf(acc1[g][r] + bb, 0.f);
            }
        }
    }
    __syncthreads();

    // ---- stage 2: K=256, 8 k-tiles ----
    f32x4 acc20[8] = {}, acc21[8] = {};
    bf16x8 ahA0, ahA1, ahB0, ahB1;

#define PF_AH(AN0, AN1, KT) { \
    AN0 = *(const bf16x8*)(sH + ((size_t)((KT) * 4 + l4) * 64 + wm * 32 + l15) * 8); \
    AN1 = *(const bf16x8*)(sH + ((size_t)((KT) * 4 + l4) * 64 + wm * 32 + 16 + l15) * 8); }

    PF_AH(ahA0, ahA1, 0)

#define S2_BODY(KT, WC, WN, AH0, AH1, AN0, AN1) { \
    if ((KT) < 7) { PF_W(WN, w2p, (KT) + 1); PF_AH(AN0, AN1, (KT) + 1); } \
    __builtin_amdgcn_s_setprio(1); \
    _Pragma("unroll") for (int g = 0; g < 8; ++g) { \
        acc20[g] = mfma16(AH0, WC[g], acc20[g]); \
        acc21[g] = mfma16(AH1, WC[g], acc21[g]); } \
    __builtin_amdgcn_s_setprio(0); }

#define S2_PAIR2(K) \
    S2_BODY(2*(K),   wA, wB, ahA0, ahA1, ahB0, ahB1) \
    S2_BODY(2*(K)+1, wB, wA, ahB0, ahB1, ahA0, ahA1)

    S2_PAIR2(0) S2_PAIR2(1) S2_PAIR2(2) S2_PAIR2(3)

    // ---- epilogue: dual-store fp32 ----
    float bias2[8];
    #pragma unroll
    for (int g = 0; g < 8; ++g) bias2[g] = b2[wn * 128 + g * 16 + l15];
    const int rw = wm * 32 + l4 * 4;
    #pragma unroll
    for (int r = 0; r < 4; ++r) {
        int ta = r_base + rw + r;
        if (ta < TRI) {
            int ij = lut[ta];
            int i = ij >> 8, j = ij & 255;
            float* o1 = Out + (size_t)((b * NRG + i) * NRG + j) * RD;
            float* o2 = Out + (size_t)((b * NRG + j) * NRG + i) * RD;
            #pragma unroll
            for (int g = 0; g < 8; ++g) {
                int col = wn * 128 + g * 16 + l15;
                float v = fmaxf(acc20[g][r] + bias2[g], 0.f);
                o1[col] = v;
                o2[col] = v;
            }
        }
        int tb = r_base + rw + 16 + r;
        if (tb < TRI) {
            int ij = lut[tb];
            int i = ij >> 8, j = ij & 255;
            float* o1 = Out + (size_t)((b * NRG + i) * NRG + j) * RD;
            float* o2 = Out + (size_t)((b * NRG + j) * NRG + i) * RD;
            #pragma unroll
            for (int g = 0; g < 8; ++g) {
                int col = wn * 128 + g * 16 + l15;
                float v = fmaxf(acc21[g][r] + bias2[g], 0.f);
                o1[col] = v;
                o2[col] = v;
            }
        }
    }
#undef PF_W
#undef PF_PAIR
#undef S1_BODY
#undef S1_PAIR2
#undef PF_AH
#undef S2_BODY
#undef S2_PAIR2
}

extern "C" void kernel_launch(void* const* d_in, const int* in_sizes, int n_in,
                              void* d_out, int out_size, void* d_ws, size_t ws_size,
                              hipStream_t stream) {
    const float* X   = (const float*)d_in[0];
    const float* Q   = (const float*)d_in[1];
    const float* pos = (const float*)d_in[2];
    const float* Wv  = (const float*)d_in[3];
    const float* bv  = (const float*)d_in[4];
    const float* Wq  = (const float*)d_in[5];
    const float* bq  = (const float*)d_in[6];
    const float* W1  = (const float*)d_in[7];
    const float* b1  = (const float*)d_in[8];
    const float* W2  = (const float*)d_in[9];
    const float* b2  = (const float*)d_in[10];

    char* ws = (char*)d_ws;
    size_t off = 0;
    auto alloc = [&](size_t bytes) {
        char* p = ws + off;
        off = (off + bytes + 255) & ~(size_t)255;
        return p;
    };
    __bf16* Xc  = (__bf16*)alloc((size_t)MR * KP * 2);
    __bf16* Wvg = (__bf16*)alloc((size_t)(KP/8) * CS * 8 * 2);
    __bf16* W1g = (__bf16*)alloc((size_t)(CS/8) * RD * 8 * 2);
    __bf16* W2g = (__bf16*)alloc((size_t)(RD/8) * RD * 8 * 2);
    float*  Qp  = (float*) alloc((size_t)BSZ * CS * 4);
    __bf16* Xs  = (__bf16*)alloc((size_t)MR * CS * 2);
    int*    lut = (int*)   alloc((size_t)TRIQ * 4);

    hipLaunchKernelGGL(k_prep, dim3(MR + 520 + 64 + 32 + 1), dim3(256), 0, stream,
                       X, pos, Wv, W1, W2, Xc, Wvg, W1g, W2g, lut);
    hipLaunchKernelGGL(k_qproj, dim3(BSZ, CS/64), dim3(256), 0, stream, Q, Wq, bq, Qp);
    hipLaunchKernelGGL(k_g1,  dim3(MR/64, CS/64), dim3(256), 0, stream,
                       Xc, Wvg, bv, Qp, Xs);
    hipLaunchKernelGGL(k_g23, dim3(TRIQ/64, BSZ), dim3(256), 0, stream,
                       Xs, W1g, W2g, b1, b2, (float*)d_out, (const int*)lut);
}

// Round 8
// 104.673 us; speedup vs baseline: 1.2376x; 1.0313x over previous
//
#include <hip/hip_runtime.h>
#include <hip/hip_bf16.h>
#include <stdint.h>

#define BSZ 64
#define NRG 36
#define VD  2048
#define QD  1024
#define CS  512
#define RD  256
#define KP  2080                 // 2052 padded to 32
#define MR  (BSZ*NRG)            // 2304
#define TRI  666                 // upper-triangle pairs (i<=j) per batch
#define TRIQ 768                 // padded per-batch rows

typedef __bf16 bf16x8 __attribute__((ext_vector_type(8)));
typedef float  f32x4  __attribute__((ext_vector_type(4)));

static __device__ __forceinline__ f32x4 mfma16(bf16x8 a, bf16x8 b, f32x4 c) {
    return __builtin_amdgcn_mfma_f32_16x16x32_bf16(a, b, c, 0, 0, 0);
}

// async global->LDS, 16B per lane (dest = wave-uniform base + lane*16)
static __device__ __forceinline__ void load_lds16(const __bf16* g, __bf16* l) {
    __builtin_amdgcn_global_load_lds(
        (const __attribute__((address_space(1))) uint32_t*)(const void*)g,
        (__attribute__((address_space(3))) uint32_t*)(void*)l,
        16, 0, 0);
}

// ---- merged prep: Xc rows, 3 g-major weights, tri LUT, one launch ----
__global__ __launch_bounds__(256) void k_prep(
    const float* __restrict__ X, const float* __restrict__ pos,
    const float* __restrict__ Wv, const float* __restrict__ W1,
    const float* __restrict__ W2,
    __bf16* __restrict__ Xc, __bf16* __restrict__ Wvg,
    __bf16* __restrict__ W1g, __bf16* __restrict__ W2g,
    int* __restrict__ lut)
{
    int id = blockIdx.x;
    if (id < MR) {               // ---- Xc row: [X | pos | 0-pad] ----
        const float* xr = X + (size_t)id * VD;
        const float* pr = pos + (size_t)id * 4;
        __bf16* o = Xc + (size_t)id * KP;
        for (int c = threadIdx.x; c < KP; c += 256) {
            float v = 0.f;
            if (c < VD) v = xr[c];
            else if (c < VD + 4) v = pr[c - VD];
            o[c] = (__bf16)v;
        }
        return;
    }
    id -= MR;
    if (id < 520 + 64 + 32) {    // ---- weight tile -> Wg[k/8][N][8] ----
        const float* W; __bf16* Wg; int K, N, nbx;
        if (id < 520)      {          W = Wv; Wg = Wvg; K = VD + 4; N = CS; nbx = CS / 64; }
        else if (id < 584) { id -= 520; W = W1; Wg = W1g; K = CS;     N = RD; nbx = RD / 64; }
        else               { id -= 584; W = W2; Wg = W2g; K = RD;     N = RD; nbx = RD / 64; }
        int bx = id % nbx, by = id / nbx;
        int g = by * 4 + (threadIdx.x >> 6);
        int n = bx * 64 + (threadIdx.x & 63);
        bf16x8 v;
        #pragma unroll
        for (int e = 0; e < 8; ++e) {
            int k = g * 8 + e;
            v[e] = (__bf16)((k < K) ? W[(size_t)k * N + n] : 0.f);
        }
        *(bf16x8*)(Wg + ((size_t)g * N + n) * 8) = v;
        return;
    }
    // ---- lut ----
    for (int t = threadIdx.x; t < TRIQ; t += 256) {
        int tt = (t < TRI) ? t : (TRI - 1);
        int i = 0;
        while (tt >= NRG - i) { tt -= NRG - i; ++i; }
        lut[t] = (i << 8) | (i + tt);
    }
}

// ---- Qp[b][c] = relu(Q[b]@Wq[:,c] + bq[c]) fp32, split-K parallel ----
__global__ __launch_bounds__(256) void k_qproj(
    const float* __restrict__ Q, const float* __restrict__ Wq,
    const float* __restrict__ bq, float* __restrict__ Qp) {
    int b   = blockIdx.x;
    int col = blockIdx.y * 64 + (threadIdx.x & 63);
    int ks  = threadIdx.x >> 6;
    const float* q = Q  + (size_t)b * QD + ks * 256;
    const float* w = Wq + (size_t)(ks * 256) * CS + col;
    float acc = 0.f;
    #pragma unroll 8
    for (int k = 0; k < 256; ++k)
        acc = fmaf(q[k], w[(size_t)k * CS], acc);
    __shared__ float red[256];
    red[threadIdx.x] = acc;
    __syncthreads();
    if (ks == 0) {
        float v = red[threadIdx.x] + red[threadIdx.x + 64]
                + red[threadIdx.x + 128] + red[threadIdx.x + 192] + bq[col];
        Qp[(size_t)b * CS + col] = fmaxf(v, 0.f);
    }
}

// ---- G1: Xs = relu(Xc @ Wv + bv) + Qp[b], ring-4 LDS, counted vmcnt ----
__global__ __launch_bounds__(256) void k_g1(
    const __bf16* __restrict__ Xc,   // [MR][KP]
    const __bf16* __restrict__ Wvg,  // [KP/8][CS][8]
    const float* __restrict__ bv,
    const float* __restrict__ Qp,    // [BSZ][CS]
    __bf16* __restrict__ Xs)         // [MR][CS]
{
    __shared__ __align__(16) __bf16 sA[4][4 * 64 * 8];
    __shared__ __align__(16) __bf16 sB[4][4 * 64 * 8];

    const int tid = threadIdx.x;
    const int lane = tid & 63;
    const int w = tid >> 6;
    const int wm = w & 1, wn = w >> 1;
    const int l15 = lane & 15, l4 = lane >> 4;
    const int m0 = blockIdx.x * 64;
    const int n0 = blockIdx.y * 64;
    const int sg = tid >> 6;
    const int sr = tid & 63;

    auto stage = [&](int kt, int slot) {
        load_lds16(Xc + (size_t)(m0 + sr) * KP + kt * 32 + sg * 8,
                   &sA[slot][0] + (size_t)tid * 8);
        load_lds16(Wvg + ((size_t)(kt * 4 + sg) * CS + n0 + sr) * 8,
                   &sB[slot][0] + (size_t)tid * 8);
    };

    constexpr int NKT = KP / 32;   // 65
    stage(0, 0);
    stage(1, 1);

    f32x4 acc[2][2] = {};
    for (int kt = 0; kt < NKT; ++kt) {
        if (kt + 2 < NKT) stage(kt + 2, (kt + 2) & 3);
        if (kt + 2 < NKT)      asm volatile("s_waitcnt vmcnt(4)" ::: "memory");
        else if (kt + 1 < NKT) asm volatile("s_waitcnt vmcnt(2)" ::: "memory");
        else                   asm volatile("s_waitcnt vmcnt(0)" ::: "memory");
        __builtin_amdgcn_s_barrier();

        const __bf16* a_base = &sA[kt & 3][0];
        const __bf16* b_base = &sB[kt & 3][0];
        bf16x8 af[2], bf[2];
        #pragma unroll
        for (int f = 0; f < 2; ++f)
            af[f] = *(const bf16x8*)(a_base + ((size_t)l4 * 64 + wm * 32 + f * 16 + l15) * 8);
        #pragma unroll
        for (int g = 0; g < 2; ++g)
            bf[g] = *(const bf16x8*)(b_base + ((size_t)l4 * 64 + wn * 32 + g * 16 + l15) * 8);
        __builtin_amdgcn_s_setprio(1);
        #pragma unroll
        for (int f = 0; f < 2; ++f)
            #pragma unroll
            for (int g = 0; g < 2; ++g)
                acc[f][g] = mfma16(af[f], bf[g], acc[f][g]);
        __builtin_amdgcn_s_setprio(0);
    }

    #pragma unroll
    for (int f = 0; f < 2; ++f) {
        int row0 = m0 + wm * 32 + f * 16 + l4 * 4;
        #pragma unroll
        for (int g = 0; g < 2; ++g) {
            int col = n0 + wn * 32 + g * 16 + l15;
            float bb = bv[col];
            #pragma unroll
            for (int r = 0; r < 4; ++r) {
                int row = row0 + r;
                float v = fmaxf(acc[f][g][r] + bb, 0.f) + Qp[(size_t)(row / NRG) * CS + col];
                Xs[(size_t)row * CS + col] = (__bf16)v;
            }
        }
    }
}

// ---- fused G2+G3 v5: Xs[b] in swizzled LDS (kills divergent loads),
//      W in named-reg ping-pong, two 32-row stage-2 passes (sH 16KB),
//      52KB LDS -> 3 blocks/CU, grid 768 = 3*256 exactly ----
__global__ __launch_bounds__(256, 3) void k_g23(
    const __bf16* __restrict__ Xs,   // [MR][CS]
    const __bf16* __restrict__ W1g,  // [CS/8][RD][8]
    const __bf16* __restrict__ W2g,  // [RD/8][RD][8]
    const float* __restrict__ b1,
    const float* __restrict__ b2,
    float* __restrict__ Out,         // [BSZ][NRG][NRG][RD]
    const int* __restrict__ lut)
{
    __shared__ __align__(16) __bf16 sXs[NRG * CS];   // 36 KB, XOR-swizzled
    __shared__ __align__(16) __bf16 sH[32 * RD];     // 16 KB [g2(32)][row(32)][8]

    const int tid = threadIdx.x;
    const int lane = tid & 63;
    const int w = tid >> 6;
    const int wm = w & 1, wn = w >> 1;   // stage1 wave = 32 rows x 128 cols
    const int l15 = lane & 15, l4 = lane >> 4;
    const int b = blockIdx.y;
    const int r_base = blockIdx.x * 64;
    const char* sXc = (const char*)sXs;

    // ---- stage Xs[b] -> LDS, swizzle byte ^= (row&7)<<4 ----
    {
        const __bf16* src = Xs + (size_t)b * NRG * CS;
        #pragma unroll
        for (int c = 0; c < 9; ++c) {
            int id = c * 256 + tid;          // 0..2303 chunks of 8 elems
            int r = id >> 6, cp = id & 63;
            bf16x8 v = *(const bf16x8*)(src + (size_t)r * CS + cp * 8);
            int ba = (r << 10) ^ ((r & 7) << 4) ^ (cp << 4);
            *(bf16x8*)((char*)sXs + ba) = v;
        }
    }

    // lut-derived swizzled row bases for the 2 M-fragments
    const int t0 = r_base + wm * 32 + l15;
    const int ij0 = lut[t0], ij1 = lut[t0 + 16];
    const int i0 = ij0 >> 8, j0 = ij0 & 255, i1 = ij1 >> 8, j1 = ij1 & 255;
    const int qi0 = (i0 << 10) ^ ((i0 & 7) << 4);
    const int qj0 = (j0 << 10) ^ ((j0 & 7) << 4);
    const int qi1 = (i1 << 10) ^ ((i1 & 7) << 4);
    const int qj1 = (j1 << 10) ^ ((j1 & 7) << 4);
    const int lc = l4 << 4;

    // per-lane W fragment bases (16B contiguous per lane, 4 cache lines/load)
    const __bf16* w1p = W1g + ((size_t)l4 * RD + wn * 128 + l15) * 8;
    const __bf16* w2q = W2g + ((size_t)l4 * RD + w * 64 + l15) * 8;

    f32x4 acc0[8] = {}, acc1[8] = {};
    bf16x8 wA[8], wB[8];

#define WTS (4 * RD * 8)
#define PF_W8(WN, KT) { \
    const __bf16* wp_ = w1p + (size_t)(KT) * WTS; \
    _Pragma("unroll") for (int g = 0; g < 8; ++g) \
        WN[g] = *(const bf16x8*)(wp_ + (size_t)g * 128); }
#define PF_W4(WN, KT) { \
    const __bf16* wp_ = w2q + (size_t)(KT) * WTS; \
    _Pragma("unroll") for (int g = 0; g < 4; ++g) \
        WN[g] = *(const bf16x8*)(wp_ + (size_t)g * 128); }

    PF_W8(wA, 0)          // overlap W1 tile0 fetch with staging
    __syncthreads();

#define S1_BODY(KT, WC, WN) { \
    const int ck_ = ((KT) * 64) | lc; \
    bf16x8 xi0_ = *(const bf16x8*)(sXc + (qi0 ^ ck_)); \
    bf16x8 xj0_ = *(const bf16x8*)(sXc + (qj0 ^ ck_)); \
    bf16x8 xi1_ = *(const bf16x8*)(sXc + (qi1 ^ ck_)); \
    bf16x8 xj1_ = *(const bf16x8*)(sXc + (qj1 ^ ck_)); \
    bf16x8 af0_, af1_; \
    _Pragma("unroll") for (int e = 0; e < 8; ++e) { \
        af0_[e] = (__bf16)((float)xi0_[e] * (float)xj0_[e]); \
        af1_[e] = (__bf16)((float)xi1_[e] * (float)xj1_[e]); } \
    if ((KT) < 15) { PF_W8(WN, (KT) + 1) } else { PF_W4(WN, 0) } \
    __builtin_amdgcn_s_setprio(1); \
    _Pragma("unroll") for (int g = 0; g < 8; ++g) { \
        acc0[g] = mfma16(af0_, WC[g], acc0[g]); \
        acc1[g] = mfma16(af1_, WC[g], acc1[g]); } \
    __builtin_amdgcn_s_setprio(0); }

    S1_BODY(0,  wA, wB) S1_BODY(1,  wB, wA) S1_BODY(2,  wA, wB) S1_BODY(3,  wB, wA)
    S1_BODY(4,  wA, wB) S1_BODY(5,  wB, wA) S1_BODY(6,  wA, wB) S1_BODY(7,  wB, wA)
    S1_BODY(8,  wA, wB) S1_BODY(9,  wB, wA) S1_BODY(10, wA, wB) S1_BODY(11, wB, wA)
    S1_BODY(12, wA, wB) S1_BODY(13, wB, wA) S1_BODY(14, wA, wB) S1_BODY(15, wB, wA)
    // after KT=15: W2 pass-tile0 (4 frags) sits in wA[0..3]

#define S2_BODY(KT, WC, WN) { \
    bf16x8 ah0_ = *(const bf16x8*)(sH + ((size_t)((KT) * 4 + l4) * 32 + l15) * 8); \
    bf16x8 ah1_ = *(const bf16x8*)(sH + ((size_t)((KT) * 4 + l4) * 32 + 16 + l15) * 8); \
    if ((KT) < 7) { PF_W4(WN, (KT) + 1) } else { PF_W4(WN, 0) } \
    __builtin_amdgcn_s_setprio(1); \
    _Pragma("unroll") for (int g = 0; g < 4; ++g) { \
        acc20[g] = mfma16(ah0_, WC[g], acc20[g]); \
        acc21[g] = mfma16(ah1_, WC[g], acc21[g]); } \
    __builtin_amdgcn_s_setprio(0); }

    #pragma unroll
    for (int p = 0; p < 2; ++p) {
        // ---- transition: owner waves (wm==p) write their H rows 0..31 ----
        if (wm == p) {
            #pragma unroll
            for (int g = 0; g < 8; ++g) {
                int col = wn * 128 + g * 16 + l15;
                float bb = b1[col];
                int g2 = col >> 3, e = col & 7;
                #pragma unroll
                for (int r = 0; r < 4; ++r) {
                    int rl = l4 * 4 + r;
                    sH[((size_t)g2 * 32 + rl) * 8 + e]      = (__bf16)fmaxf(acc0[g][r] + bb, 0.f);
                    sH[((size_t)g2 * 32 + 16 + rl) * 8 + e] = (__bf16)fmaxf(acc1[g][r] + bb, 0.f);
                }
            }
        }
        __syncthreads();

        // ---- stage 2 pass p: 32 rows x 256 cols, wave = 32r x 64c ----
        f32x4 acc20[4] = {}, acc21[4] = {};
        S2_BODY(0, wA, wB) S2_BODY(1, wB, wA) S2_BODY(2, wA, wB) S2_BODY(3, wB, wA)
        S2_BODY(4, wA, wB) S2_BODY(5, wB, wA) S2_BODY(6, wA, wB) S2_BODY(7, wB, wA)
        // KT=7 re-prefetched tile0 into wA for the next pass

        // ---- epilogue: dual-store fp32 ----
        float b2c[4];
        #pragma unroll
        for (int g = 0; g < 4; ++g) b2c[g] = b2[w * 64 + g * 16 + l15];
        #pragma unroll
        for (int r = 0; r < 4; ++r) {
            int ta = r_base + p * 32 + l4 * 4 + r;          // m=0 rows
            if (ta < TRI) {
                int ij = lut[ta]; int i = ij >> 8, j = ij & 255;
                float* o1 = Out + ((size_t)((b * NRG + i) * NRG + j)) * RD;
                float* o2 = Out + ((size_t)((b * NRG + j) * NRG + i)) * RD;
                #pragma unroll
                for (int g = 0; g < 4; ++g) {
                    int col = w * 64 + g * 16 + l15;
                    float v = fmaxf(acc20[g][r] + b2c[g], 0.f);
                    o1[col] = v; o2[col] = v;
                }
            }
            int tb = r_base + p * 32 + 16 + l4 * 4 + r;     // m=1 rows
            if (tb < TRI) {
                int ij = lut[tb]; int i = ij >> 8, j = ij & 255;
                float* o1 = Out + ((size_t)((b * NRG + i) * NRG + j)) * RD;
                float* o2 = Out + ((size_t)((b * NRG + j) * NRG + i)) * RD;
                #pragma unroll
                for (int g = 0; g < 4; ++g) {
                    int col = w * 64 + g * 16 + l15;
                    float v = fmaxf(acc21[g][r] + b2c[g], 0.f);
                    o1[col] = v; o2[col] = v;
                }
            }
        }
        __syncthreads();   // protect sH before next pass's transition
    }
#undef WTS
#undef PF_W8
#undef PF_W4
#undef S1_BODY
#undef S2_BODY
}

extern "C" void kernel_launch(void* const* d_in, const int* in_sizes, int n_in,
                              void* d_out, int out_size, void* d_ws, size_t ws_size,
                              hipStream_t stream) {
    const float* X   = (const float*)d_in[0];
    const float* Q   = (const float*)d_in[1];
    const float* pos = (const float*)d_in[2];
    const float* Wv  = (const float*)d_in[3];
    const float* bv  = (const float*)d_in[4];
    const float* Wq  = (const float*)d_in[5];
    const float* bq  = (const float*)d_in[6];
    const float* W1  = (const float*)d_in[7];
    const float* b1  = (const float*)d_in[8];
    const float* W2  = (const float*)d_in[9];
    const float* b2  = (const float*)d_in[10];

    char* ws = (char*)d_ws;
    size_t off = 0;
    auto alloc = [&](size_t bytes) {
        char* p = ws + off;
        off = (off + bytes + 255) & ~(size_t)255;
        return p;
    };
    __bf16* Xc  = (__bf16*)alloc((size_t)MR * KP * 2);
    __bf16* Wvg = (__bf16*)alloc((size_t)(KP/8) * CS * 8 * 2);
    __bf16* W1g = (__bf16*)alloc((size_t)(CS/8) * RD * 8 * 2);
    __bf16* W2g = (__bf16*)alloc((size_t)(RD/8) * RD * 8 * 2);
    float*  Qp  = (float*) alloc((size_t)BSZ * CS * 4);
    __bf16* Xs  = (__bf16*)alloc((size_t)MR * CS * 2);
    int*    lut = (int*)   alloc((size_t)TRIQ * 4);

    hipLaunchKernelGGL(k_prep, dim3(MR + 520 + 64 + 32 + 1), dim3(256), 0, stream,
                       X, pos, Wv, W1, W2, Xc, Wvg, W1g, W2g, lut);
    hipLaunchKernelGGL(k_qproj, dim3(BSZ, CS/64), dim3(256), 0, stream, Q, Wq, bq, Qp);
    hipLaunchKernelGGL(k_g1,  dim3(MR/64, CS/64), dim3(256), 0, stream,
                       Xc, Wvg, bv, Qp, Xs);
    hipLaunchKernelGGL(k_g23, dim3(TRIQ/64, BSZ), dim3(256), 0, stream,
                       Xs, W1g, W2g, b1, b2, (float*)d_out, (const int*)lut);
}